// Round 6
// baseline (314.505 us; speedup 1.0000x reference)
//
#include <hip/hip_runtime.h>

typedef _Float16 f16;
typedef _Float16 half2v __attribute__((ext_vector_type(2)));
typedef _Float16 half4v __attribute__((ext_vector_type(4)));
typedef _Float16 half8 __attribute__((ext_vector_type(8)));
typedef float f32x4 __attribute__((ext_vector_type(4)));

#define MFMA16(a, b, c) __builtin_amdgcn_mfma_f32_16x16x32_f16((a), (b), (c), 0, 0, 0)

// Sizes: B=4, CI=64, H=W=128 ; conv out 64x64 ; C=160 ; S=4097 ; SQ=4096 ; NH=4 ; HD=40
// q layout: [bh(16)][s(4097)][40] f16 packed (no d-pad; MFMA k 40..63 fed from LDS zero blk)
// k layout: [bh(16)][s(4160)][40] f16 packed (rows 4097.. uninit, masked on last tile)
// vt layout: [bh(16)][d(40)][4160] f16
// pacc: [ks(2)][bh(16)][q(4096)][48] f32 partial o; col 40 = partial l (ones-column trick)
// Softmax: P = exp2(s*scale*log2e - mfix), mfix = |q|*maxK*scale*log2e - 14 (Cauchy-Schwarz
// bound; Delta=14 keeps f16 P out of subnormals, P <= 2^14 < 65504). Fixed shift => K-split
// partials combine linearly: o = o0+o1, l = l0+l1.

// ---------------- K0: prep (w2 transpose, f pad row, maxk2 init) ----------------
__global__ __launch_bounds__(256) void k_prep(
    const float* __restrict__ w2, const float* __restrict__ pe,
    float* __restrict__ w2t, f16* __restrict__ f_h, int* __restrict__ maxk2) {
  int i = blockIdx.x * 256 + threadIdx.x;
  if (i < 10240) {                       // w2t[co][c2] = w2[c2][co]
    int co = i / 160, c2 = i - co * 160;
    w2t[co * 160 + c2] = w2[c2 * 64 + co];
  } else if (i < 10880) {                // f[b][4096][c] = pe[4096]
    int j = i - 10240;
    int bb = j / 160, c = j - bb * 160;
    f_h[(bb * 4097 + 4096) * 160 + c] = (f16)pe[4096];
  } else if (i < 10896) {                // maxk2 init (0 as int == 0.0f; sums are > 0)
    maxk2[i - 10880] = 0;
  }
}

// ---------------- K1: conv1(2x2 s2) + b1 + conv2(1x1) + b2 + leaky + pe -> f fp16 -------
__global__ __launch_bounds__(256) void k_conv(
    const float* __restrict__ x, const float* __restrict__ w1, const float* __restrict__ b1,
    const float* __restrict__ w2t, const float* __restrict__ b2, const float* __restrict__ pe,
    f16* __restrict__ f_h) {
  __shared__ float xin[32 * 4 * 64];
  __shared__ float c1[64 * 64];
  int y = blockIdx.x, b = blockIdx.y;
  int t = threadIdx.x, lane = t & 63, wv = t >> 6;
  const float* xb = x + (b * 64) * 16384 + (2 * y) * 128;

  int cob = __builtin_amdgcn_readfirstlane(wv * 16);
  float acc[16];
#pragma unroll
  for (int j = 0; j < 16; ++j) acc[j] = b1[cob + j];

  for (int half = 0; half < 2; ++half) {
    __syncthreads();
    for (int k = 0; k < 32; ++k) {
      int i = t + (k << 8);
      int cil = i >> 8, rem = i & 255, r = rem >> 7, col = rem & 127;
      xin[(cil * 4 + r * 2 + (col & 1)) * 64 + (col >> 1)] =
          xb[(half * 32 + cil) * 16384 + r * 128 + col];
    }
    __syncthreads();
    for (int cil = 0; cil < 32; ++cil) {
      int ci = half * 32 + cil;
      float x00 = xin[(cil * 4 + 0) * 64 + lane];
      float x01 = xin[(cil * 4 + 1) * 64 + lane];
      float x10 = xin[(cil * 4 + 2) * 64 + lane];
      float x11 = xin[(cil * 4 + 3) * 64 + lane];
      const float* wr = w1 + (cob * 64 + ci) * 4;
#pragma unroll
      for (int j = 0; j < 16; ++j) {
        acc[j] += wr[j * 256 + 0] * x00 + wr[j * 256 + 1] * x01 +
                  wr[j * 256 + 2] * x10 + wr[j * 256 + 3] * x11;
      }
    }
  }
#pragma unroll
  for (int j = 0; j < 16; ++j) c1[(cob + j) * 64 + lane] = acc[j];
  __syncthreads();

  int c2b = __builtin_amdgcn_readfirstlane(wv * 40);
  float a2[40];
#pragma unroll
  for (int j = 0; j < 40; ++j) a2[j] = b2[c2b + j];
  for (int co = 0; co < 64; ++co) {
    float xv = c1[co * 64 + lane];
    const float* wr = w2t + co * 160 + c2b;
#pragma unroll
    for (int j = 0; j < 40; ++j) a2[j] += xv * wr[j];
  }
  int s = y * 64 + lane;
  float pes = pe[s];
  f16* dst = f_h + (b * 4097 + s) * 160 + c2b;
#pragma unroll
  for (int j = 0; j < 40; ++j) {
    float v = a2[j];
    v = (v >= 0.f) ? v : 0.01f * v;
    v += pes;
    dst[j] = (f16)v;
  }
}

// ---------------- K2: QKV gemms via MFMA (f32 weights converted during staging) ---------
__global__ __launch_bounds__(256) void k_qkv(
    const f16* __restrict__ f_h,
    const float* __restrict__ wq, const float* __restrict__ wk, const float* __restrict__ wv,
    f16* __restrict__ q_h, f16* __restrict__ k_h, f16* __restrict__ vt_h) {
  __shared__ __attribute__((aligned(16))) f16 fT[64 * 168];
  __shared__ __attribute__((aligned(16))) f16 wT[80 * 168];
  int sb = blockIdx.x, b = blockIdx.y;
  int s0 = sb * 64;
  int t = threadIdx.x, lane = t & 63, wv2 = t >> 6, quad = lane >> 4, col = lane & 15;

  for (int c = t; c < 1280; c += 256) {
    int row = c / 20, seg = c - row * 20;
    int srow = s0 + row; if (srow > 4096) srow = 4096;
    *(uint4*)(fT + row * 168 + seg * 8) =
        *(const uint4*)(f_h + (b * 4097 + srow) * 160 + seg * 8);
  }
  __syncthreads();
  half8 af[5];
  int rowA = wv2 * 16 + col;
#pragma unroll
  for (int kk = 0; kk < 5; ++kk)
    af[kk] = *(half8*)(fT + rowA * 168 + kk * 32 + quad * 8);

  for (int kind = 0; kind < 3; ++kind) {
    const float* wsp = (kind == 0) ? wq : (kind == 1 ? wk : wv);
    for (int hf = 0; hf < 2; ++hf) {
      __syncthreads();
      for (int c = t; c < 1600; c += 256) {
        int row = c / 20, seg = c - row * 20;
        const float* src = wsp + (hf * 80 + row) * 160 + seg * 8;
        f32x4 va = *(const f32x4*)src;
        f32x4 vb = *(const f32x4*)(src + 4);
        uint4 u;
        u.x = __builtin_bit_cast(unsigned, __builtin_amdgcn_cvt_pkrtz(va[0], va[1]));
        u.y = __builtin_bit_cast(unsigned, __builtin_amdgcn_cvt_pkrtz(va[2], va[3]));
        u.z = __builtin_bit_cast(unsigned, __builtin_amdgcn_cvt_pkrtz(vb[0], vb[1]));
        u.w = __builtin_bit_cast(unsigned, __builtin_amdgcn_cvt_pkrtz(vb[2], vb[3]));
        *(uint4*)(wT + row * 168 + seg * 8) = u;
      }
      __syncthreads();
#pragma unroll
      for (int n0 = 0; n0 < 5; ++n0) {
        f32x4 acc; acc[0] = 0.f; acc[1] = 0.f; acc[2] = 0.f; acc[3] = 0.f;
        int rowB = n0 * 16 + col;
#pragma unroll
        for (int kk = 0; kk < 5; ++kk) {
          half8 bf = *(half8*)(wT + rowB * 168 + kk * 32 + quad * 8);
          acc = MFMA16(af[kk], bf, acc);
        }
        int o = (hf * 5 + n0) * 16 + col;
        int hh = o / 40, d = o - hh * 40;
        int bh = b * 4 + hh;
#pragma unroll
        for (int r = 0; r < 4; ++r) {
          int s = s0 + wv2 * 16 + quad * 4 + r;
          if (s <= 4096) {
            f16 v = (f16)acc[r];
            if (kind == 0)      q_h[((size_t)bh * 4097 + s) * 40 + d] = v;
            else if (kind == 1) k_h[((size_t)bh * 4160 + s) * 40 + d] = v;
            else                vt_h[((size_t)bh * 40 + d) * 4160 + s] = v;
          }
        }
      }
    }
  }
}

// ---------------- K2b: per-head max ||k||^2 (packed stride 40) ----------------
__global__ __launch_bounds__(256) void k_norm1(const f16* __restrict__ k_h,
                                               int* __restrict__ maxk2) {
  int bh = blockIdx.x >> 3, chunk = blockIdx.x & 7;
  int t = threadIdx.x;
  int lo = chunk * 513, hi = lo + 513; if (hi > 4097) hi = 4097;
  float mx = 0.f;
  for (int i = lo + t; i < hi; i += 256) {
    const f16* kr = k_h + ((size_t)bh * 4160 + i) * 40;
    float s = 0.f;
#pragma unroll
    for (int c = 0; c < 5; ++c) {
      half8 v = *(const half8*)(kr + c * 8);
#pragma unroll
      for (int j = 0; j < 8; ++j) { float f = (float)v[j]; s += f * f; }
    }
    mx = fmaxf(mx, s);
  }
#pragma unroll
  for (int d = 1; d < 64; d <<= 1) mx = fmaxf(mx, __shfl_xor(mx, d));
  __shared__ float red[4];
  if ((t & 63) == 0) red[t >> 6] = mx;
  __syncthreads();
  if (t == 0) {
    float m = fmaxf(fmaxf(red[0], red[1]), fmaxf(red[2], red[3]));
    atomicMax(maxk2 + bh, __float_as_int(m));
  }
}

// ---------------- K3: flash attention, K-split x2, packed d40, direct-V ----------------
// grid (32 qt, 16 bh, 2 ks). 4 waves x 32 q = 128 q/block; ks halves split the K range
// (tiles 0..32 / 33..64); partials (o,l) combine linearly thanks to the fixed shift.
// One barrier/iter (K dbuf + reg prefetch makes the second barrier redundant).
__global__ __launch_bounds__(256, 4) void k_attn(
    const f16* __restrict__ q_h, const f16* __restrict__ k_h,
    const f16* __restrict__ vt_h, const int* __restrict__ maxk2,
    float* __restrict__ pacc) {
  __shared__ __attribute__((aligned(16))) f16 Ks[2][64 * 40];  // packed flat K tile, dbuf
  __shared__ __attribute__((aligned(16))) f16 Zro[8];          // shared zero blk (k 40..63)
  __shared__ __attribute__((aligned(16))) f16 Ps[4 * 32 * 72]; // per-wave P; doubles as Q stage

  int qt = blockIdx.x, bh = blockIdx.y, ks = blockIdx.z;
  int qbase = qt * 128;
  int t = threadIdx.x, lane = t & 63, wv = t >> 6, quad = lane >> 4, col = lane & 15;
  const float c1l = 0.15811388300841898f * 1.4426950408889634f;  // scale*log2e
  int gbase = ks * 33;
  int nIter = 33 - ks;  // 33 / 32 tiles

  // ---- stage Q packed [128][40] into Ps; zero blk ----
  const f16* qb = q_h + ((size_t)bh * 4097 + qbase) * 40;
  for (int c = t; c < 640; c += 256)
    *(uint4*)(Ps + c * 8) = *(const uint4*)(qb + c * 8);
  if (t < 8) Zro[t] = (f16)0;

  // ---- K tile 0 register prefetch (flat 5120 B = 320 x 16 B) ----
  const f16* khb = k_h + ((size_t)bh * 4160 + gbase * 64) * 40;
  uint4 rka = *(const uint4*)(khb + t * 8);
  uint4 rkb = {0, 0, 0, 0};
  if (t < 64) rkb = *(const uint4*)(khb + (256 + t) * 8);
  __syncthreads();

  // ---- Q fragments + per-row mfix (fused k_norm2) ----
  half8 bq[2][2];
  float mfl[2];
  float mk = __int_as_float(maxk2[bh]);
#pragma unroll
  for (int nt = 0; nt < 2; ++nt) {
    int row = wv * 32 + nt * 16 + col;
    bq[nt][0] = *(half8*)(Ps + row * 40 + quad * 8);
    const f16* p1 = (quad == 0) ? (Ps + row * 40 + 32) : Zro;
    bq[nt][1] = *(half8*)p1;
    float s = 0.f;
#pragma unroll
    for (int j = 0; j < 8; ++j) {
      float a0 = (float)bq[nt][0][j], a1 = (float)bq[nt][1][j];
      s += a0 * a0 + a1 * a1;
    }
    s += __shfl_xor(s, 16);
    s += __shfl_xor(s, 32);
    mfl[nt] = sqrtf(s * mk) * c1l - 14.0f;  // Delta=14 anti-subnormal boost
  }

  f32x4 o_[2][3];
#pragma unroll
  for (int a = 0; a < 2; ++a)
#pragma unroll
    for (int b2 = 0; b2 < 3; ++b2)
#pragma unroll
      for (int r = 0; r < 4; ++r) o_[a][b2][r] = 0.f;

  f16* Pw = Ps + wv * (32 * 72);
  const uint4 vones = {0x3C003C00u, 0x3C003C00u, 0x3C003C00u, 0x3C003C00u};
  const uint4 vzero = {0u, 0u, 0u, 0u};

  for (int kt = 0; kt < nIter; ++kt) {
    int bsel = kt & 1;
    int g = gbase + kt;
    // write prefetched K tile (flat) into LDS buffer bsel
    *(uint4*)(&Ks[bsel][t * 8]) = rka;
    if (t < 64) *(uint4*)(&Ks[bsel][(256 + t) * 8]) = rkb;
    // prefetch next K tile into regs
    if (kt + 1 < nIter) {
      const f16* kn = khb + (size_t)(kt + 1) * 2560;
      rka = *(const uint4*)(kn + t * 8);
      if (t < 64) rkb = *(const uint4*)(kn + (256 + t) * 8);
    }
    // V B-fragments for CURRENT tile, direct global->reg (latency hidden by S+exp)
    uint4 bvr[3][2];
    int k0 = g << 6;
#pragma unroll
    for (int nv = 0; nv < 3; ++nv) {
      int d = nv * 16 + col;
#pragma unroll
      for (int kk2 = 0; kk2 < 2; ++kk2) {
        if (d < 40)
          bvr[nv][kk2] =
              *(const uint4*)(vt_h + ((size_t)bh * 40 + d) * 4160 + k0 + kk2 * 32 + quad * 8);
        else
          bvr[nv][kk2] = (d == 40) ? vones : vzero;  // ones-col accumulates l
      }
    }
    __syncthreads();

    // ---- S^T: acc[mt][nt] ----
    f32x4 acc[4][2];
#pragma unroll
    for (int mt = 0; mt < 4; ++mt) {
      int row = mt * 16 + col;
      half8 ak0 = *(half8*)(&Ks[bsel][row * 40 + quad * 8]);
      const f16* pa1 = (quad == 0) ? &Ks[bsel][row * 40 + 32] : Zro;
      half8 ak1 = *(half8*)pa1;
#pragma unroll
      for (int nt = 0; nt < 2; ++nt) {
        f32x4 a; a[0] = 0.f; a[1] = 0.f; a[2] = 0.f; a[3] = 0.f;
        a = MFMA16(ak0, bq[nt][0], a);
        a = MFMA16(ak1, bq[nt][1], a);
        acc[mt][nt] = a;
      }
    }
    bool lastt = (g == 64);
    // ---- P = exp2(s*c1l - mfix) (bound guarantees arg <= 14; no clamp needed) ----
#pragma unroll
    for (int mt = 0; mt < 4; ++mt)
#pragma unroll
      for (int nt = 0; nt < 2; ++nt) {
        float p[4];
#pragma unroll
        for (int r = 0; r < 4; ++r) {
          p[r] = __builtin_amdgcn_exp2f(fmaf(acc[mt][nt][r], c1l, -mfl[nt]));
          if (lastt && (mt * 16 + quad * 4 + r) != 0) p[r] = 0.f;  // keys > 4096
        }
        half2v lo = __builtin_bit_cast(half2v, __builtin_amdgcn_cvt_pkrtz(p[0], p[1]));
        half2v hi = __builtin_bit_cast(half2v, __builtin_amdgcn_cvt_pkrtz(p[2], p[3]));
        half4v pk; pk.lo = lo; pk.hi = hi;
        *(half4v*)(Pw + (nt * 16 + col) * 72 + mt * 16 + quad * 4) = pk;
      }
    // ---- o += P·V^T ----
#pragma unroll
    for (int kk2 = 0; kk2 < 2; ++kk2) {
      half8 ap0 = *(half8*)(Pw + col * 72 + kk2 * 32 + quad * 8);
      half8 ap1 = *(half8*)(Pw + (16 + col) * 72 + kk2 * 32 + quad * 8);
#pragma unroll
      for (int nv = 0; nv < 3; ++nv) {
        half8 bv = __builtin_bit_cast(half8, bvr[nv][kk2]);
        o_[0][nv] = MFMA16(ap0, bv, o_[0][nv]);
        o_[1][nv] = MFMA16(ap1, bv, o_[1][nv]);
      }
    }
  }

  // ---- epilogue: store partial o (cols 0..39) + partial l (col 40) ----
  float* pb = pacc + (size_t)(ks * 16 + bh) * 4096 * 48;
#pragma unroll
  for (int mtq = 0; mtq < 2; ++mtq)
#pragma unroll
    for (int nv = 0; nv < 3; ++nv)
#pragma unroll
      for (int r = 0; r < 4; ++r) {
        int q = qbase + wv * 32 + mtq * 16 + quad * 4 + r;
        pb[(size_t)q * 48 + nv * 16 + col] = o_[mtq][nv][r];
      }
}

// ---------------- K4: combine K-split partials + LayerNorm + residual + upsample --------
__global__ __launch_bounds__(256) void k_ln_out(
    const float* __restrict__ pacc, const float* __restrict__ lnw,
    const float* __restrict__ lnb, float* __restrict__ out) {
  __shared__ float g[64 * 161];
  __shared__ float linv[64 * 4];
  int y = blockIdx.x, b = blockIdx.y, t = threadIdx.x;
  const size_t P1 = (size_t)16 * 4096 * 48;
  {
    int row = t >> 2, h = t & 3;
    size_t i0 = ((size_t)(b * 4 + h) * 4096 + y * 64 + row) * 48 + 40;
    linv[row * 4 + h] = 1.f / (pacc[i0] + pacc[P1 + i0]);
  }
  __syncthreads();
  for (int i = t; i < 10240; i += 256) {
    int row = i / 160, c = i - row * 160;
    int h = c / 40, d = c - h * 40;
    size_t idx = ((size_t)(b * 4 + h) * 4096 + y * 64 + row) * 48 + d;
    g[row * 161 + c] = (pacc[idx] + pacc[P1 + idx]) * linv[row * 4 + h];
  }
  __syncthreads();
  int row = t >> 2, part = t & 3;
  float* gr = g + row * 161 + part * 40;
  float s1 = 0.f, s2 = 0.f;
#pragma unroll
  for (int j = 0; j < 40; ++j) { float v = gr[j]; s1 += v; s2 += v * v; }
  s1 += __shfl_xor(s1, 1); s1 += __shfl_xor(s1, 2);
  s2 += __shfl_xor(s2, 1); s2 += __shfl_xor(s2, 2);
  float mu = s1 * (1.f / 160.f);
  float var = s2 * (1.f / 160.f) - mu * mu;
  float inv = rsqrtf(var + 1e-5f);
  const float* lw = lnw + part * 40;
  const float* lb = lnb + part * 40;
#pragma unroll
  for (int j = 0; j < 40; ++j) {
    float v = gr[j];
    gr[j] = (v - mu) * inv * lw[j] + lb[j] + v;
  }
  __syncthreads();
  int Yo = t >> 7, X = t & 127, rl = X >> 1;
  float* ob = out + ((b * 160) * 128 + (2 * y + Yo)) * 128 + X;
#pragma unroll 4
  for (int c = 0; c < 160; ++c) ob[c * 16384] = g[rl * 161 + c];
}

extern "C" void kernel_launch(void* const* d_in, const int* in_sizes, int n_in,
                              void* d_out, int out_size, void* d_ws, size_t ws_size,
                              hipStream_t stream) {
  const float* x   = (const float*)d_in[0];
  const float* w1  = (const float*)d_in[1];
  const float* b1  = (const float*)d_in[2];
  const float* w2  = (const float*)d_in[3];
  const float* b2  = (const float*)d_in[4];
  const float* pe  = (const float*)d_in[5];
  const float* wq  = (const float*)d_in[6];
  const float* wk  = (const float*)d_in[7];
  const float* wvp = (const float*)d_in[8];
  const float* lnw = (const float*)d_in[9];
  const float* lnb = (const float*)d_in[10];
  float* out = (float*)d_out;

  char* p = (char*)d_ws;
  f16* f_h   = (f16*)p;   p += 4 * 4097 * 160 * 2;        // 5,244,160
  float* w2t = (float*)p; p += 64 * 160 * 4;              // 40,960
  f16* q_h   = (f16*)p;   p += (size_t)16 * 4097 * 40 * 2;  // 5,244,160
  f16* k_h   = (f16*)p;   p += (size_t)16 * 4160 * 40 * 2;  // 5,324,800
  f16* vt_h  = (f16*)p;   p += (size_t)16 * 40 * 4160 * 2;  // 5,324,800
  float* pacc = (float*)p; p += (size_t)2 * 16 * 4096 * 48 * 4;  // 25,165,824
  int* maxk2 = (int*)p;   p += 16 * 4;
  // total ~46.3 MB

  k_prep<<<43, 256, 0, stream>>>(w2, pe, w2t, f_h, maxk2);
  k_conv<<<dim3(64, 4), 256, 0, stream>>>(x, w1, b1, w2t, b2, pe, f_h);
  k_qkv<<<dim3(65, 4), 256, 0, stream>>>(f_h, wq, wk, wvp, q_h, k_h, vt_h);
  k_norm1<<<128, 256, 0, stream>>>(k_h, maxk2);
  k_attn<<<dim3(32, 16, 2), 256, 0, stream>>>(q_h, k_h, vt_h, maxk2, pacc);
  k_ln_out<<<dim3(64, 4), 256, 0, stream>>>(pacc, lnw, lnb, out);
}